// Round 2
// baseline (649.934 us; speedup 1.0000x reference)
//
#include <hip/hip_runtime.h>
#include <math.h>

#define N_  4
#define P_  20000
#define DIN 1024
#define K_  8
#define DH  64
#define BP  64      // patches per block (1 wave = 16 rows; 4 waves = 64 rows)
#define NT  5       // 5 col-tiles of 16: cols 0-63 = W_pre, 64-71 = centroids, 72-79 pad

typedef float  f32x4 __attribute__((ext_vector_type(4)));
typedef short  s16x8 __attribute__((ext_vector_type(8)));
typedef unsigned int u32x4 __attribute__((ext_vector_type(4)));
typedef unsigned short ushort_t;

// ws layout (float offsets). NEEDS ws_size >= 344064 bytes.
//   [0,2048)      gsum   per-(n,k,j) cluster sums
//   [2048,2080)   gcnt   per-(n,k) counts (int)
//   [2080,2088)   c2     ||centroid_k||^2
//   [4096,45056)  Bth    bf16-hi plane of B^T  [80 cols][1024 k] (ushort)
//   [45056,86016) Btl    bf16-lo plane of B^T  (ushort)

union FragU { u32x4 u; s16x8 s; };

// blocks 0..79: build B^T bf16 hi/lo planes; block 80: zero accumulators + c2
__global__ __launch_bounds__(512) void k_pre(const float* __restrict__ W_pre,
                                             const float* __restrict__ centroids,
                                             float* __restrict__ ws) {
  const int t = threadIdx.x;
  const int b = blockIdx.x;
  if (b < 80) {
    const int c = b;
    ushort_t* Bth = (ushort_t*)(ws + 4096);
    ushort_t* Btl = (ushort_t*)(ws + 45056);
    for (int d = t; d < DIN; d += 512) {
      float v = 0.f;
      if (c < 64)      v = W_pre[(size_t)d * DH + c];
      else if (c < 72) v = centroids[(size_t)(c - 64) * DIN + d];
      unsigned u = __float_as_uint(v);
      unsigned r = u + 0x7FFFu + ((u >> 16) & 1u);     // RTN to bf16
      unsigned hb = r & 0xFFFF0000u;
      float lo = v - __uint_as_float(hb);
      unsigned ul = __float_as_uint(lo);
      unsigned rl = ul + 0x7FFFu + ((ul >> 16) & 1u);
      Bth[(size_t)c * DIN + d] = (ushort_t)(hb >> 16);
      Btl[(size_t)c * DIN + d] = (ushort_t)(rl >> 16);
    }
  } else {
    int* gcnt = (int*)(ws + 2048);
    for (int i = t; i < N_ * K_ * DH; i += 512) ws[i] = 0.f;
    if (t < N_ * K_) gcnt[t] = 0;
    const int w = t >> 6, lane = t & 63;
    float s = 0.f;
    for (int d = lane; d < DIN; d += 64) {
      float v = centroids[(size_t)w * DIN + d];
      s += v * v;
    }
    for (int off = 32; off > 0; off >>= 1) s += __shfl_down(s, off, 64);
    if (lane == 0) ws[2080 + w] = s;
  }
}

// split one 8-float row-slice into truncated-bf16 hi plane + truncated lo plane
__device__ __forceinline__ void cvt_split(const f32x4 a0, const f32x4 a1,
                                          FragU& ah, FragU& al) {
  float f[8];
#pragma unroll
  for (int e = 0; e < 4; ++e) { f[e] = a0[e]; f[4 + e] = a1[e]; }
#pragma unroll
  for (int q = 0; q < 4; ++q) {
    const unsigned u0 = __float_as_uint(f[2 * q]);
    const unsigned u1 = __float_as_uint(f[2 * q + 1]);
    ah.u[q] = (u0 >> 16) | (u1 & 0xFFFF0000u);           // hi = trunc-bf16
    const float l0 = f[2 * q]     - __uint_as_float(u0 & 0xFFFF0000u);
    const float l1 = f[2 * q + 1] - __uint_as_float(u1 & 0xFFFF0000u);
    al.u[q] = (__float_as_uint(l0) >> 16) | (__float_as_uint(l1) & 0xFFFF0000u);
  }
}

// Barrier-free K-loop, BP=64: 1252 blocks (4.9/CU) so memory latency is hidden
// by wave residency instead of staging. Each lane streams its own A-row from
// global; B from the L2-resident bf16 planes. LDS holds only the epilogue tile.
__global__ __launch_bounds__(256, 5) void k_main(
    const float* __restrict__ x, const float* __restrict__ b_pre,
    float* __restrict__ out1, float* __restrict__ out2, float* __restrict__ ws) {
  __shared__ float xp[BP * 65];      // xp tile, stride 65 (bank-conflict pad)
  __shared__ float sc[BP * 9];
  __shared__ int   assign_s[BP];
  __shared__ int   cnt8[K_];

  const int t = threadIdx.x;
  const int w = t >> 6, l = t & 63;
  const int m = l & 15, q4 = l >> 4;
  const int n = blockIdx.y;
  const int p0 = blockIdx.x * BP;
  const int validP = (P_ - p0) < BP ? (P_ - p0) : BP;

  const ushort_t* Bth = (const ushort_t*)(ws + 4096);
  const ushort_t* Btl = (const ushort_t*)(ws + 45056);

  if (t < K_) cnt8[t] = 0;

  f32x4 acc[NT];
#pragma unroll
  for (int tl = 0; tl < NT; ++tl) acc[tl] = (f32x4){0.f, 0.f, 0.f, 0.f};

  // per-lane A row pointer: lane (m,q4) owns row 16w+m, k-slice q4*8..+8.
  // ks*32-float step = ks*128 B <= 3968 -> whole K-loop folds to imm offsets.
  const int r0 = p0 + 16 * w + m;
  const int g0 = r0 < P_ ? r0 : P_ - 1;
  const float* ap0 = x + (size_t)n * P_ * DIN + (size_t)g0 * DIN + q4 * 8;

  const ushort_t* bhp[NT];
  const ushort_t* blp[NT];
#pragma unroll
  for (int tl = 0; tl < NT; ++tl) {
    const size_t off = (size_t)(tl * 16 + m) * DIN + q4 * 8;
    bhp[tl] = Bth + off;
    blp[tl] = Btl + off;
  }

#pragma unroll 4
  for (int ks = 0; ks < 32; ++ks) {
    const int ko = ks * 32;
    const f32x4 a00 = *(const f32x4*)(ap0 + ko);
    const f32x4 a01 = *(const f32x4*)(ap0 + ko + 4);
    FragU bh[NT], bl[NT];
#pragma unroll
    for (int tl = 0; tl < NT; ++tl) {
      bh[tl].u = *(const u32x4*)(bhp[tl] + ko);
      bl[tl].u = *(const u32x4*)(blp[tl] + ko);
    }
    FragU ah0, al0;
    cvt_split(a00, a01, ah0, al0);
    // product order per acc stays hh -> hl -> lh (bitwise-identical results)
#pragma unroll
    for (int tl = 0; tl < NT; ++tl)
      acc[tl] = __builtin_amdgcn_mfma_f32_16x16x32_bf16(ah0.s, bh[tl].s, acc[tl], 0, 0, 0);
#pragma unroll
    for (int tl = 0; tl < NT; ++tl)
      acc[tl] = __builtin_amdgcn_mfma_f32_16x16x32_bf16(ah0.s, bl[tl].s, acc[tl], 0, 0, 0);
#pragma unroll
    for (int tl = 0; tl < NT; ++tl)
      acc[tl] = __builtin_amdgcn_mfma_f32_16x16x32_bf16(al0.s, bh[tl].s, acc[tl], 0, 0, 0);
  }

  // epilogue: bias+relu, write enc_seq twice, xp -> LDS
#pragma unroll
  for (int tl = 0; tl < 4; ++tl) {
    const int col = tl * 16 + m;
    const float bb = b_pre[col];
#pragma unroll
    for (int r = 0; r < 4; ++r) {
      const int row = 16 * w + (q4 << 2) + r;   // C layout: row=(lane>>4)*4+reg
      float v = acc[tl][r] + bb;
      v = v > 0.f ? v : 0.f;
      xp[row * 65 + col] = v;
      if (row < validP) {
        const size_t o = (((size_t)(n * P_ + p0 + row)) << 6) + col;
        out1[o] = v;
        out2[o] = v;
      }
    }
  }
  // scores from col-tile 4 (cols 64-71 = centroid dots)
  if (m < K_) {
    const float cc = ws[2080 + m];
#pragma unroll
    for (int r = 0; r < 4; ++r) {
      const int row = 16 * w + (q4 << 2) + r;
      sc[row * 9 + m] = cc - 2.f * acc[4][r];
    }
  }
  __syncthreads();

  if (t < BP) {
    int a = -1;
    if (t < validP) {
      float best = 3.4e38f; int bk = 0;
#pragma unroll
      for (int k = 0; k < K_; ++k) {
        const float v = sc[t * 9 + k];
        if (v < best) { best = v; bk = k; }
      }
      a = bk;
      atomicAdd(&cnt8[bk], 1);
    }
    assign_s[t] = a;
  }
  __syncthreads();

  // per-block cluster sums -> one atomic per (k,j)
  for (int task = t; task < K_ * DH; task += 256) {
    const int k = task >> 6, j = task & 63;
    float s = 0.f;
    for (int p = 0; p < BP; ++p)
      s += (assign_s[p] == k) ? xp[p * 65 + j] : 0.f;
    if (s != 0.f) atomicAdd(&ws[(n * K_ + k) * DH + j], s);
  }
  if (t < K_ && cnt8[t] > 0) atomicAdd((int*)(ws + 2048) + n * K_ + t, cnt8[t]);
}

__global__ __launch_bounds__(256) void k_final(
    const float* __restrict__ W_a1, const float* __restrict__ b_a1,
    const float* __restrict__ W_a2, const float* __restrict__ b_a2,
    const float* __restrict__ W_out, const float* __restrict__ b_out,
    const float* __restrict__ ws, float* __restrict__ enc_cls) {
  __shared__ float xc[N_ * K_ * DH];
  __shared__ float zs[N_ * K_ * 32];
  __shared__ float wa[N_ * K_];
  __shared__ float As[N_ * K_];
  __shared__ int   cnts[N_ * K_];
  __shared__ float pooled[N_ * DH];
  const int t = threadIdx.x;
  const float* gsum = ws;
  const int* gcnt = (const int*)(ws + 2048);

  if (t < N_ * K_) cnts[t] = gcnt[t];
  __syncthreads();
  for (int i = t; i < N_ * K_ * DH; i += 256) {
    const int nk = i >> 6;
    const int c = cnts[nk];
    xc[i] = (c > 0) ? gsum[i] / (float)c : 0.f;
  }
  __syncthreads();
  // attention hidden layer: 1024 independent (nk,h) tasks across 256 threads
  for (int i = t; i < N_ * K_ * 32; i += 256) {
    const int nk = i >> 5, h = i & 31;
    float z = b_a1[h];
    for (int j = 0; j < DH; ++j) z += xc[nk * DH + j] * W_a1[j * 32 + h];
    zs[i] = tanhf(z) * W_a2[h];
  }
  __syncthreads();
  if (t < N_ * K_) {
    float a = b_a2[0];
    for (int h = 0; h < 32; ++h) a += zs[t * 32 + h];
    As[t] = (cnts[t] > 0) ? a : -100000.f;
  }
  __syncthreads();
  if (t < N_) {
    float mx = -3.4e38f;
    for (int k = 0; k < K_; ++k) mx = fmaxf(mx, As[t * K_ + k]);
    float ssum = 0.f;
    float e[K_];
    for (int k = 0; k < K_; ++k) { e[k] = expf(As[t * K_ + k] - mx); ssum += e[k]; }
    for (int k = 0; k < K_; ++k) wa[t * K_ + k] = e[k] / ssum;
  }
  __syncthreads();
  {
    const int n = t >> 6, j = t & 63;
    float s = 0.f;
    for (int k = 0; k < K_; ++k) s += xc[(n * K_ + k) * DH + j] * wa[n * K_ + k];
    pooled[t] = s;
  }
  __syncthreads();
  if (t < N_ * 32) {
    const int n = t >> 5, o = t & 31;
    float s = b_out[o];
    for (int j = 0; j < DH; ++j) s += pooled[n * DH + j] * W_out[j * 32 + o];
    enc_cls[n * 32 + o] = fmaxf(s, 0.f);
  }
}

extern "C" void kernel_launch(void* const* d_in, const int* in_sizes, int n_in,
                              void* d_out, int out_size, void* d_ws, size_t ws_size,
                              hipStream_t stream) {
  const float* x         = (const float*)d_in[0];
  const float* centroids = (const float*)d_in[1];
  const float* W_pre     = (const float*)d_in[2];
  const float* b_pre     = (const float*)d_in[3];
  const float* W_a1      = (const float*)d_in[4];
  const float* b_a1      = (const float*)d_in[5];
  const float* W_a2      = (const float*)d_in[6];
  const float* b_a2      = (const float*)d_in[7];
  const float* W_out     = (const float*)d_in[8];
  const float* b_out     = (const float*)d_in[9];

  float* out     = (float*)d_out;
  float* ws      = (float*)d_ws;
  float* enc_cls = out;
  float* out1    = out + N_ * 32;
  float* out2    = out + N_ * 32 + (size_t)N_ * P_ * DH;

  hipLaunchKernelGGL(k_pre, dim3(81), dim3(512), 0, stream, W_pre, centroids, ws);
  hipLaunchKernelGGL(k_main, dim3((P_ + BP - 1) / BP, N_), dim3(256), 0, stream,
                     x, b_pre, out1, out2, ws);
  hipLaunchKernelGGL(k_final, dim3(1), dim3(256), 0, stream,
                     W_a1, b_a1, W_a2, b_a2, W_out, b_out, ws, enc_cls);
}

// Round 3
// 565.580 us; speedup vs baseline: 1.1491x; 1.1491x over previous
//
#include <hip/hip_runtime.h>
#include <math.h>

#define N_  4
#define P_  20000
#define DIN 1024
#define K_  8
#define DH  64
#define BP  128     // patches per block (wave owns 32 rows: 2 x 16-row groups)
#define NT  5       // 5 col-tiles of 16: cols 0-63 = W_pre, 64-71 = centroids, 72-79 pad

typedef float  f32x4 __attribute__((ext_vector_type(4)));
typedef short  s16x8 __attribute__((ext_vector_type(8)));
typedef unsigned int u32x4 __attribute__((ext_vector_type(4)));
typedef unsigned short ushort_t;

// ws layout (float offsets). NEEDS ws_size >= 344064 bytes.
//   [0,2048)      gsum   per-(n,k,j) cluster sums
//   [2048,2080)   gcnt   per-(n,k) counts (int)
//   [2080,2088)   c2     ||centroid_k||^2
//   [4096,45056)  Bth    bf16-hi plane of B^T  [80 cols][1024 k] (ushort)
//   [45056,86016) Btl    bf16-lo plane of B^T  (ushort)

union FragU { u32x4 u; s16x8 s; };

// blocks 0..79: build B^T bf16 hi/lo planes; block 80: zero accumulators + c2
__global__ __launch_bounds__(512) void k_pre(const float* __restrict__ W_pre,
                                             const float* __restrict__ centroids,
                                             float* __restrict__ ws) {
  const int t = threadIdx.x;
  const int b = blockIdx.x;
  if (b < 80) {
    const int c = b;
    ushort_t* Bth = (ushort_t*)(ws + 4096);
    ushort_t* Btl = (ushort_t*)(ws + 45056);
    for (int d = t; d < DIN; d += 512) {
      float v = 0.f;
      if (c < 64)      v = W_pre[(size_t)d * DH + c];
      else if (c < 72) v = centroids[(size_t)(c - 64) * DIN + d];
      unsigned u = __float_as_uint(v);
      unsigned r = u + 0x7FFFu + ((u >> 16) & 1u);     // RTN to bf16
      unsigned hb = r & 0xFFFF0000u;
      float lo = v - __uint_as_float(hb);
      unsigned ul = __float_as_uint(lo);
      unsigned rl = ul + 0x7FFFu + ((ul >> 16) & 1u);
      Bth[(size_t)c * DIN + d] = (ushort_t)(hb >> 16);
      Btl[(size_t)c * DIN + d] = (ushort_t)(rl >> 16);
    }
  } else {
    int* gcnt = (int*)(ws + 2048);
    for (int i = t; i < N_ * K_ * DH; i += 512) ws[i] = 0.f;
    if (t < N_ * K_) gcnt[t] = 0;
    const int w = t >> 6, lane = t & 63;
    float s = 0.f;
    for (int d = lane; d < DIN; d += 64) {
      float v = centroids[(size_t)w * DIN + d];
      s += v * v;
    }
    for (int off = 32; off > 0; off >>= 1) s += __shfl_down(s, off, 64);
    if (lane == 0) ws[2080 + w] = s;
  }
}

// split one 8-float row-slice into truncated-bf16 hi plane + truncated lo plane
__device__ __forceinline__ void cvt_split(const f32x4 a0, const f32x4 a1,
                                          FragU& ah, FragU& al) {
  float f[8];
#pragma unroll
  for (int e = 0; e < 4; ++e) { f[e] = a0[e]; f[4 + e] = a1[e]; }
#pragma unroll
  for (int q = 0; q < 4; ++q) {
    const unsigned u0 = __float_as_uint(f[2 * q]);
    const unsigned u1 = __float_as_uint(f[2 * q + 1]);
    ah.u[q] = (u0 >> 16) | (u1 & 0xFFFF0000u);           // hi = trunc-bf16
    const float l0 = f[2 * q]     - __uint_as_float(u0 & 0xFFFF0000u);
    const float l1 = f[2 * q + 1] - __uint_as_float(u1 & 0xFFFF0000u);
    al.u[q] = (__float_as_uint(l0) >> 16) | (__float_as_uint(l1) & 0xFFFF0000u);
  }
}

// One K-step of the software pipeline.
//   - issues the 10 B-frag loads (L2-resident) for THIS step
//   - converts this step's x (already in the stage regs) to bf16 hi/lo
//   - if PF: re-issues the stage regs with x for step ks+2 (2-deep HBM prefetch)
//   - runs the 30 MFMAs (they wait only on the B loads; x prefetch stays in flight)
// Accumulation order per acc is hh -> hl -> lh, tl ascending: bitwise-identical
// to the previous rounds.
template<bool PF>
__device__ __forceinline__ void kstep(
    int ko, int kpo,
    f32x4& A00, f32x4& A01, f32x4& A10, f32x4& A11,
    const float* __restrict__ ap0, const float* __restrict__ ap1,
    const ushort_t* const* bhp, const ushort_t* const* blp,
    f32x4 acc[2][NT]) {
  FragU bh[NT], bl[NT];
#pragma unroll
  for (int tl = 0; tl < NT; ++tl) {
    bh[tl].u = *(const u32x4*)(bhp[tl] + ko);
    bl[tl].u = *(const u32x4*)(blp[tl] + ko);
  }
  FragU ah0, al0, ah1, al1;
  cvt_split(A00, A01, ah0, al0);
  cvt_split(A10, A11, ah1, al1);
  if (PF) {
    A00 = *(const f32x4*)(ap0 + kpo);
    A01 = *(const f32x4*)(ap0 + kpo + 4);
    A10 = *(const f32x4*)(ap1 + kpo);
    A11 = *(const f32x4*)(ap1 + kpo + 4);
  }
#pragma unroll
  for (int tl = 0; tl < NT; ++tl) {
    acc[0][tl] = __builtin_amdgcn_mfma_f32_16x16x32_bf16(ah0.s, bh[tl].s, acc[0][tl], 0, 0, 0);
    acc[1][tl] = __builtin_amdgcn_mfma_f32_16x16x32_bf16(ah1.s, bh[tl].s, acc[1][tl], 0, 0, 0);
  }
#pragma unroll
  for (int tl = 0; tl < NT; ++tl) {
    acc[0][tl] = __builtin_amdgcn_mfma_f32_16x16x32_bf16(ah0.s, bl[tl].s, acc[0][tl], 0, 0, 0);
    acc[1][tl] = __builtin_amdgcn_mfma_f32_16x16x32_bf16(ah1.s, bl[tl].s, acc[1][tl], 0, 0, 0);
  }
#pragma unroll
  for (int tl = 0; tl < NT; ++tl) {
    acc[0][tl] = __builtin_amdgcn_mfma_f32_16x16x32_bf16(al0.s, bh[tl].s, acc[0][tl], 0, 0, 0);
    acc[1][tl] = __builtin_amdgcn_mfma_f32_16x16x32_bf16(al1.s, bh[tl].s, acc[1][tl], 0, 0, 0);
  }
}

// Barrier-free K-loop, BP=128 (best traffic shape: 30 MFMA per 14 loads),
// hand-software-pipelined: 2-deep x prefetch (HBM), per-step batched B loads
// (L2). Grid caps occupancy at 2.45 blocks/CU, so VGPRs up to ~170 are free.
__global__ __launch_bounds__(256, 3) void k_main(
    const float* __restrict__ x, const float* __restrict__ b_pre,
    float* __restrict__ out1, float* __restrict__ out2, float* __restrict__ ws) {
  __shared__ float xp[BP * 65];      // xp tile, stride 65 (bank-conflict pad)
  __shared__ float sc[BP * 9];
  __shared__ int   assign_s[BP];
  __shared__ int   cnt8[K_];

  const int t = threadIdx.x;
  const int w = t >> 6, l = t & 63;
  const int m = l & 15, q4 = l >> 4;
  const int n = blockIdx.y;
  const int p0 = blockIdx.x * BP;
  const int validP = (P_ - p0) < BP ? (P_ - p0) : BP;

  const ushort_t* Bth = (const ushort_t*)(ws + 4096);
  const ushort_t* Btl = (const ushort_t*)(ws + 45056);

  if (t < K_) cnt8[t] = 0;

  f32x4 acc[2][NT];
#pragma unroll
  for (int rg = 0; rg < 2; ++rg)
#pragma unroll
    for (int tl = 0; tl < NT; ++tl) acc[rg][tl] = (f32x4){0.f, 0.f, 0.f, 0.f};

  // per-lane A row pointers: lane (m,q4) owns rows 32w+m and 32w+16+m,
  // k-slice q4*8..+8 within each 32-float K-step.
  const int r0 = p0 + 32 * w + m;
  const int r1 = r0 + 16;
  const int g0 = r0 < P_ ? r0 : P_ - 1;
  const int g1 = r1 < P_ ? r1 : P_ - 1;
  const float* xbase = x + (size_t)n * P_ * DIN + q4 * 8;
  const float* ap0 = xbase + (size_t)g0 * DIN;
  const float* ap1 = xbase + (size_t)g1 * DIN;

  const ushort_t* bhp[NT];
  const ushort_t* blp[NT];
#pragma unroll
  for (int tl = 0; tl < NT; ++tl) {
    const size_t off = (size_t)(tl * 16 + m) * DIN + q4 * 8;
    bhp[tl] = Bth + off;
    blp[tl] = Btl + off;
  }

  // prologue: fill stage 0 (ks=0) and stage 1 (ks=1)
  f32x4 X000 = *(const f32x4*)(ap0);      f32x4 X001 = *(const f32x4*)(ap0 + 4);
  f32x4 X010 = *(const f32x4*)(ap1);      f32x4 X011 = *(const f32x4*)(ap1 + 4);
  f32x4 X100 = *(const f32x4*)(ap0 + 32); f32x4 X101 = *(const f32x4*)(ap0 + 36);
  f32x4 X110 = *(const f32x4*)(ap1 + 32); f32x4 X111 = *(const f32x4*)(ap1 + 36);

  for (int ks = 0; ks < 28; ks += 2) {
    kstep<true>(ks * 32, (ks + 2) * 32, X000, X001, X010, X011, ap0, ap1, bhp, blp, acc);
    kstep<true>((ks + 1) * 32, (ks + 3) * 32, X100, X101, X110, X111, ap0, ap1, bhp, blp, acc);
  }
  kstep<true >(28 * 32, 30 * 32, X000, X001, X010, X011, ap0, ap1, bhp, blp, acc);
  kstep<true >(29 * 32, 31 * 32, X100, X101, X110, X111, ap0, ap1, bhp, blp, acc);
  kstep<false>(30 * 32, 0,       X000, X001, X010, X011, ap0, ap1, bhp, blp, acc);
  kstep<false>(31 * 32, 0,       X100, X101, X110, X111, ap0, ap1, bhp, blp, acc);

  // epilogue: bias+relu, write enc_seq twice, xp -> LDS
#pragma unroll
  for (int tl = 0; tl < 4; ++tl) {
    const int col = tl * 16 + m;
    const float bb = b_pre[col];
#pragma unroll
    for (int rg = 0; rg < 2; ++rg) {
#pragma unroll
      for (int r = 0; r < 4; ++r) {
        const int row = 32 * w + 16 * rg + (q4 << 2) + r;   // C layout: row=(lane>>4)*4+reg
        float v = acc[rg][tl][r] + bb;
        v = v > 0.f ? v : 0.f;
        xp[row * 65 + col] = v;
        if (row < validP) {
          const size_t o = (((size_t)(n * P_ + p0 + row)) << 6) + col;
          out1[o] = v;
          out2[o] = v;
        }
      }
    }
  }
  // scores from col-tile 4 (cols 64-71 = centroid dots)
  if (m < K_) {
    const float cc = ws[2080 + m];
#pragma unroll
    for (int rg = 0; rg < 2; ++rg)
#pragma unroll
      for (int r = 0; r < 4; ++r) {
        const int row = 32 * w + 16 * rg + (q4 << 2) + r;
        sc[row * 9 + m] = cc - 2.f * acc[rg][4][r];
      }
  }
  __syncthreads();

  if (t < BP) {
    int a = -1;
    if (t < validP) {
      float best = 3.4e38f; int bk = 0;
#pragma unroll
      for (int k = 0; k < K_; ++k) {
        const float v = sc[t * 9 + k];
        if (v < best) { best = v; bk = k; }
      }
      a = bk;
      atomicAdd(&cnt8[bk], 1);
    }
    assign_s[t] = a;
  }
  __syncthreads();

  // per-block cluster sums -> one atomic per (k,j)
  for (int task = t; task < K_ * DH; task += 256) {
    const int k = task >> 6, j = task & 63;
    float s = 0.f;
    for (int p = 0; p < BP; ++p)
      s += (assign_s[p] == k) ? xp[p * 65 + j] : 0.f;
    if (s != 0.f) atomicAdd(&ws[(n * K_ + k) * DH + j], s);
  }
  if (t < K_ && cnt8[t] > 0) atomicAdd((int*)(ws + 2048) + n * K_ + t, cnt8[t]);
}

__global__ __launch_bounds__(256) void k_final(
    const float* __restrict__ W_a1, const float* __restrict__ b_a1,
    const float* __restrict__ W_a2, const float* __restrict__ b_a2,
    const float* __restrict__ W_out, const float* __restrict__ b_out,
    const float* __restrict__ ws, float* __restrict__ enc_cls) {
  __shared__ float xc[N_ * K_ * DH];
  __shared__ float zs[N_ * K_ * 32];
  __shared__ float wa[N_ * K_];
  __shared__ float As[N_ * K_];
  __shared__ int   cnts[N_ * K_];
  __shared__ float pooled[N_ * DH];
  const int t = threadIdx.x;
  const float* gsum = ws;
  const int* gcnt = (const int*)(ws + 2048);

  if (t < N_ * K_) cnts[t] = gcnt[t];
  __syncthreads();
  for (int i = t; i < N_ * K_ * DH; i += 256) {
    const int nk = i >> 6;
    const int c = cnts[nk];
    xc[i] = (c > 0) ? gsum[i] / (float)c : 0.f;
  }
  __syncthreads();
  // attention hidden layer: 1024 independent (nk,h) tasks across 256 threads
  for (int i = t; i < N_ * K_ * 32; i += 256) {
    const int nk = i >> 5, h = i & 31;
    float z = b_a1[h];
    for (int j = 0; j < DH; ++j) z += xc[nk * DH + j] * W_a1[j * 32 + h];
    zs[i] = tanhf(z) * W_a2[h];
  }
  __syncthreads();
  if (t < N_ * K_) {
    float a = b_a2[0];
    for (int h = 0; h < 32; ++h) a += zs[t * 32 + h];
    As[t] = (cnts[t] > 0) ? a : -100000.f;
  }
  __syncthreads();
  if (t < N_) {
    float mx = -3.4e38f;
    for (int k = 0; k < K_; ++k) mx = fmaxf(mx, As[t * K_ + k]);
    float ssum = 0.f;
    float e[K_];
    for (int k = 0; k < K_; ++k) { e[k] = expf(As[t * K_ + k] - mx); ssum += e[k]; }
    for (int k = 0; k < K_; ++k) wa[t * K_ + k] = e[k] / ssum;
  }
  __syncthreads();
  {
    const int n = t >> 6, j = t & 63;
    float s = 0.f;
    for (int k = 0; k < K_; ++k) s += xc[(n * K_ + k) * DH + j] * wa[n * K_ + k];
    pooled[t] = s;
  }
  __syncthreads();
  if (t < N_ * 32) {
    const int n = t >> 5, o = t & 31;
    float s = b_out[o];
    for (int j = 0; j < DH; ++j) s += pooled[n * DH + j] * W_out[j * 32 + o];
    enc_cls[n * 32 + o] = fmaxf(s, 0.f);
  }
}

extern "C" void kernel_launch(void* const* d_in, const int* in_sizes, int n_in,
                              void* d_out, int out_size, void* d_ws, size_t ws_size,
                              hipStream_t stream) {
  const float* x         = (const float*)d_in[0];
  const float* centroids = (const float*)d_in[1];
  const float* W_pre     = (const float*)d_in[2];
  const float* b_pre     = (const float*)d_in[3];
  const float* W_a1      = (const float*)d_in[4];
  const float* b_a1      = (const float*)d_in[5];
  const float* W_a2      = (const float*)d_in[6];
  const float* b_a2      = (const float*)d_in[7];
  const float* W_out     = (const float*)d_in[8];
  const float* b_out     = (const float*)d_in[9];

  float* out     = (float*)d_out;
  float* ws      = (float*)d_ws;
  float* enc_cls = out;
  float* out1    = out + N_ * 32;
  float* out2    = out + N_ * 32 + (size_t)N_ * P_ * DH;

  hipLaunchKernelGGL(k_pre, dim3(81), dim3(512), 0, stream, W_pre, centroids, ws);
  hipLaunchKernelGGL(k_main, dim3((P_ + BP - 1) / BP, N_), dim3(256), 0, stream,
                     x, b_pre, out1, out2, ws);
  hipLaunchKernelGGL(k_final, dim3(1), dim3(256), 0, stream,
                     W_a1, b_a1, W_a2, b_a2, W_out, b_out, ws, enc_cls);
}

// Round 4
// 561.760 us; speedup vs baseline: 1.1570x; 1.0068x over previous
//
#include <hip/hip_runtime.h>
#include <math.h>

#define N_  4
#define P_  20000
#define DIN 1024
#define K_  8
#define DH  64
#define BP  128     // patches per block (wave owns 32 rows: 2 x 16-row groups)
#define NT  5       // 5 col-tiles of 16: cols 0-63 = W_pre, 64-71 = centroids, 72-79 pad

typedef float  f32x4 __attribute__((ext_vector_type(4)));
typedef short  s16x8 __attribute__((ext_vector_type(8)));
typedef unsigned int u32x4 __attribute__((ext_vector_type(4)));
typedef unsigned short ushort_t;

// ws layout (float offsets). NEEDS ws_size >= 344064 bytes.
//   [0,2048)      gsum   per-(n,k,j) cluster sums
//   [2048,2080)   gcnt   per-(n,k) counts (int)
//   [2080,2088)   c2     ||centroid_k||^2
//   [4096,45056)  Bth    bf16-hi plane of B^T  [80 cols][1024 k] (ushort)
//   [45056,86016) Btl    bf16-lo plane of B^T  (ushort)

union FragU { u32x4 u; s16x8 s; };

// blocks 0..79: build B^T bf16 hi/lo planes; block 80: zero accumulators + c2
__global__ __launch_bounds__(512) void k_pre(const float* __restrict__ W_pre,
                                             const float* __restrict__ centroids,
                                             float* __restrict__ ws) {
  const int t = threadIdx.x;
  const int b = blockIdx.x;
  if (b < 80) {
    const int c = b;
    ushort_t* Bth = (ushort_t*)(ws + 4096);
    ushort_t* Btl = (ushort_t*)(ws + 45056);
    for (int d = t; d < DIN; d += 512) {
      float v = 0.f;
      if (c < 64)      v = W_pre[(size_t)d * DH + c];
      else if (c < 72) v = centroids[(size_t)(c - 64) * DIN + d];
      unsigned u = __float_as_uint(v);
      unsigned r = u + 0x7FFFu + ((u >> 16) & 1u);     // RTN to bf16
      unsigned hb = r & 0xFFFF0000u;
      float lo = v - __uint_as_float(hb);
      unsigned ul = __float_as_uint(lo);
      unsigned rl = ul + 0x7FFFu + ((ul >> 16) & 1u);
      Bth[(size_t)c * DIN + d] = (ushort_t)(hb >> 16);
      Btl[(size_t)c * DIN + d] = (ushort_t)(rl >> 16);
    }
  } else {
    int* gcnt = (int*)(ws + 2048);
    for (int i = t; i < N_ * K_ * DH; i += 512) ws[i] = 0.f;
    if (t < N_ * K_) gcnt[t] = 0;
    const int w = t >> 6, lane = t & 63;
    float s = 0.f;
    for (int d = lane; d < DIN; d += 64) {
      float v = centroids[(size_t)w * DIN + d];
      s += v * v;
    }
    for (int off = 32; off > 0; off >>= 1) s += __shfl_down(s, off, 64);
    if (lane == 0) ws[2080 + w] = s;
  }
}

// split one 8-float row-slice into truncated-bf16 hi plane + truncated lo plane
__device__ __forceinline__ void cvt_split(const f32x4 a0, const f32x4 a1,
                                          FragU& ah, FragU& al) {
  float f[8];
#pragma unroll
  for (int e = 0; e < 4; ++e) { f[e] = a0[e]; f[4 + e] = a1[e]; }
#pragma unroll
  for (int q = 0; q < 4; ++q) {
    const unsigned u0 = __float_as_uint(f[2 * q]);
    const unsigned u1 = __float_as_uint(f[2 * q + 1]);
    ah.u[q] = (u0 >> 16) | (u1 & 0xFFFF0000u);           // hi = trunc-bf16
    const float l0 = f[2 * q]     - __uint_as_float(u0 & 0xFFFF0000u);
    const float l1 = f[2 * q + 1] - __uint_as_float(u1 & 0xFFFF0000u);
    al.u[q] = (__float_as_uint(l0) >> 16) | (__float_as_uint(l1) & 0xFFFF0000u);
  }
}

// One K-step with register double-buffered B:
//   bhC/blC = this step's B frags (loaded one step ago, in flight or ready)
//   bhN/blN = next step's B frags (issued here if PFB)
//   X0..X3  = this step's x (consumed by cvt; reloaded with x[step+2] if PFX)
// The sched_barrier(0) pins all load issues ABOVE the MFMA block, so the
// compiler's waitcnt before the MFMAs is a counted vmcnt(14) (B-cur is older
// than the 14 just-issued loads), never a drain. MFMA order per acc stays
// hh -> hl -> lh, tl ascending: bitwise-identical to previous rounds.
template<bool PFB, bool PFX>
__device__ __forceinline__ void kstep(
    int kob, int kox,
    FragU* bhC, FragU* blC, FragU* bhN, FragU* blN,
    f32x4& X0, f32x4& X1, f32x4& X2, f32x4& X3,
    const float* __restrict__ ap0, const float* __restrict__ ap1,
    const ushort_t* const* bhp, const ushort_t* const* blp,
    f32x4 acc[2][NT]) {
  if (PFB) {
#pragma unroll
    for (int tl = 0; tl < NT; ++tl) {
      bhN[tl].u = *(const u32x4*)(bhp[tl] + kob);
      blN[tl].u = *(const u32x4*)(blp[tl] + kob);
    }
  }
  FragU ah0, al0, ah1, al1;
  cvt_split(X0, X1, ah0, al0);
  cvt_split(X2, X3, ah1, al1);
  if (PFX) {
    X0 = *(const f32x4*)(ap0 + kox);
    X1 = *(const f32x4*)(ap0 + kox + 4);
    X2 = *(const f32x4*)(ap1 + kox);
    X3 = *(const f32x4*)(ap1 + kox + 4);
  }
  __builtin_amdgcn_sched_barrier(0);
#pragma unroll
  for (int tl = 0; tl < NT; ++tl) {
    acc[0][tl] = __builtin_amdgcn_mfma_f32_16x16x32_bf16(ah0.s, bhC[tl].s, acc[0][tl], 0, 0, 0);
    acc[1][tl] = __builtin_amdgcn_mfma_f32_16x16x32_bf16(ah1.s, bhC[tl].s, acc[1][tl], 0, 0, 0);
  }
#pragma unroll
  for (int tl = 0; tl < NT; ++tl) {
    acc[0][tl] = __builtin_amdgcn_mfma_f32_16x16x32_bf16(ah0.s, blC[tl].s, acc[0][tl], 0, 0, 0);
    acc[1][tl] = __builtin_amdgcn_mfma_f32_16x16x32_bf16(ah1.s, blC[tl].s, acc[1][tl], 0, 0, 0);
  }
#pragma unroll
  for (int tl = 0; tl < NT; ++tl) {
    acc[0][tl] = __builtin_amdgcn_mfma_f32_16x16x32_bf16(al0.s, bhC[tl].s, acc[0][tl], 0, 0, 0);
    acc[1][tl] = __builtin_amdgcn_mfma_f32_16x16x32_bf16(al1.s, bhC[tl].s, acc[1][tl], 0, 0, 0);
  }
}

// Barrier-free K-loop, BP=128, register double-buffered B (1-deep) + x (2-deep).
// Grid caps occupancy at 8 waves/CU, and the VGPR cliff to 8 waves/CU is at
// 256 regs -- so the ~200-reg schedule is free. launch_bounds(256,2) tells the
// allocator so.
__global__ __launch_bounds__(256, 2) void k_main(
    const float* __restrict__ x, const float* __restrict__ b_pre,
    float* __restrict__ out1, float* __restrict__ out2, float* __restrict__ ws) {
  __shared__ float xp[BP * 65];      // xp tile, stride 65 (bank-conflict pad)
  __shared__ float sc[BP * 9];
  __shared__ int   assign_s[BP];
  __shared__ int   cnt8[K_];

  const int t = threadIdx.x;
  const int w = t >> 6, l = t & 63;
  const int m = l & 15, q4 = l >> 4;
  const int n = blockIdx.y;
  const int p0 = blockIdx.x * BP;
  const int validP = (P_ - p0) < BP ? (P_ - p0) : BP;

  const ushort_t* Bth = (const ushort_t*)(ws + 4096);
  const ushort_t* Btl = (const ushort_t*)(ws + 45056);

  if (t < K_) cnt8[t] = 0;

  f32x4 acc[2][NT];
#pragma unroll
  for (int rg = 0; rg < 2; ++rg)
#pragma unroll
    for (int tl = 0; tl < NT; ++tl) acc[rg][tl] = (f32x4){0.f, 0.f, 0.f, 0.f};

  // per-lane A row pointers: lane (m,q4) owns rows 32w+m and 32w+16+m,
  // k-slice q4*8..+8 within each 32-float K-step.
  const int r0 = p0 + 32 * w + m;
  const int r1 = r0 + 16;
  const int g0 = r0 < P_ ? r0 : P_ - 1;
  const int g1 = r1 < P_ ? r1 : P_ - 1;
  const float* xbase = x + (size_t)n * P_ * DIN + q4 * 8;
  const float* ap0 = xbase + (size_t)g0 * DIN;
  const float* ap1 = xbase + (size_t)g1 * DIN;

  const ushort_t* bhp[NT];
  const ushort_t* blp[NT];
#pragma unroll
  for (int tl = 0; tl < NT; ++tl) {
    const size_t off = (size_t)(tl * 16 + m) * DIN + q4 * 8;
    bhp[tl] = Bth + off;
    blp[tl] = Btl + off;
  }

  // register double-buffers
  FragU bhA[NT], blA[NT], bhB[NT], blB[NT];
  f32x4 Xa0, Xa1, Xa2, Xa3, Xb0, Xb1, Xb2, Xb3;

  // prologue: B[0] -> A-buf; x[0] -> Xa; x[1] -> Xb
#pragma unroll
  for (int tl = 0; tl < NT; ++tl) {
    bhA[tl].u = *(const u32x4*)(bhp[tl]);
    blA[tl].u = *(const u32x4*)(blp[tl]);
  }
  Xa0 = *(const f32x4*)(ap0);      Xa1 = *(const f32x4*)(ap0 + 4);
  Xa2 = *(const f32x4*)(ap1);      Xa3 = *(const f32x4*)(ap1 + 4);
  Xb0 = *(const f32x4*)(ap0 + 32); Xb1 = *(const f32x4*)(ap0 + 36);
  Xb2 = *(const f32x4*)(ap1 + 32); Xb3 = *(const f32x4*)(ap1 + 36);

  // main loop: steps ks (A-buf, Xa) and ks+1 (B-buf, Xb), full prefetch
  for (int ks = 0; ks < 28; ks += 2) {
    kstep<true, true>((ks + 1) * 32, (ks + 2) * 32,
                      bhA, blA, bhB, blB, Xa0, Xa1, Xa2, Xa3,
                      ap0, ap1, bhp, blp, acc);
    kstep<true, true>((ks + 2) * 32, (ks + 3) * 32,
                      bhB, blB, bhA, blA, Xb0, Xb1, Xb2, Xb3,
                      ap0, ap1, bhp, blp, acc);
  }
  // peel: steps 28..31
  kstep<true, true >(29 * 32, 30 * 32, bhA, blA, bhB, blB, Xa0, Xa1, Xa2, Xa3,
                     ap0, ap1, bhp, blp, acc);
  kstep<true, true >(30 * 32, 31 * 32, bhB, blB, bhA, blA, Xb0, Xb1, Xb2, Xb3,
                     ap0, ap1, bhp, blp, acc);
  kstep<true, false>(31 * 32, 0,       bhA, blA, bhB, blB, Xa0, Xa1, Xa2, Xa3,
                     ap0, ap1, bhp, blp, acc);
  kstep<false, false>(0, 0,            bhB, blB, bhA, blA, Xb0, Xb1, Xb2, Xb3,
                     ap0, ap1, bhp, blp, acc);

  // epilogue: bias+relu, write enc_seq twice, xp -> LDS
#pragma unroll
  for (int tl = 0; tl < 4; ++tl) {
    const int col = tl * 16 + m;
    const float bb = b_pre[col];
#pragma unroll
    for (int rg = 0; rg < 2; ++rg) {
#pragma unroll
      for (int r = 0; r < 4; ++r) {
        const int row = 32 * w + 16 * rg + (q4 << 2) + r;   // C layout: row=(lane>>4)*4+reg
        float v = acc[rg][tl][r] + bb;
        v = v > 0.f ? v : 0.f;
        xp[row * 65 + col] = v;
        if (row < validP) {
          const size_t o = (((size_t)(n * P_ + p0 + row)) << 6) + col;
          out1[o] = v;
          out2[o] = v;
        }
      }
    }
  }
  // scores from col-tile 4 (cols 64-71 = centroid dots)
  if (m < K_) {
    const float cc = ws[2080 + m];
#pragma unroll
    for (int rg = 0; rg < 2; ++rg)
#pragma unroll
      for (int r = 0; r < 4; ++r) {
        const int row = 32 * w + 16 * rg + (q4 << 2) + r;
        sc[row * 9 + m] = cc - 2.f * acc[rg][4][r];
      }
  }
  __syncthreads();

  if (t < BP) {
    int a = -1;
    if (t < validP) {
      float best = 3.4e38f; int bk = 0;
#pragma unroll
      for (int k = 0; k < K_; ++k) {
        const float v = sc[t * 9 + k];
        if (v < best) { best = v; bk = k; }
      }
      a = bk;
      atomicAdd(&cnt8[bk], 1);
    }
    assign_s[t] = a;
  }
  __syncthreads();

  // per-block cluster sums -> one atomic per (k,j)
  for (int task = t; task < K_ * DH; task += 256) {
    const int k = task >> 6, j = task & 63;
    float s = 0.f;
    for (int p = 0; p < BP; ++p)
      s += (assign_s[p] == k) ? xp[p * 65 + j] : 0.f;
    if (s != 0.f) atomicAdd(&ws[(n * K_ + k) * DH + j], s);
  }
  if (t < K_ && cnt8[t] > 0) atomicAdd((int*)(ws + 2048) + n * K_ + t, cnt8[t]);
}

__global__ __launch_bounds__(256) void k_final(
    const float* __restrict__ W_a1, const float* __restrict__ b_a1,
    const float* __restrict__ W_a2, const float* __restrict__ b_a2,
    const float* __restrict__ W_out, const float* __restrict__ b_out,
    const float* __restrict__ ws, float* __restrict__ enc_cls) {
  __shared__ float xc[N_ * K_ * DH];
  __shared__ float zs[N_ * K_ * 32];
  __shared__ float wa[N_ * K_];
  __shared__ float As[N_ * K_];
  __shared__ int   cnts[N_ * K_];
  __shared__ float pooled[N_ * DH];
  const int t = threadIdx.x;
  const float* gsum = ws;
  const int* gcnt = (const int*)(ws + 2048);

  if (t < N_ * K_) cnts[t] = gcnt[t];
  __syncthreads();
  for (int i = t; i < N_ * K_ * DH; i += 256) {
    const int nk = i >> 6;
    const int c = cnts[nk];
    xc[i] = (c > 0) ? gsum[i] / (float)c : 0.f;
  }
  __syncthreads();
  // attention hidden layer: 1024 independent (nk,h) tasks across 256 threads
  for (int i = t; i < N_ * K_ * 32; i += 256) {
    const int nk = i >> 5, h = i & 31;
    float z = b_a1[h];
    for (int j = 0; j < DH; ++j) z += xc[nk * DH + j] * W_a1[j * 32 + h];
    zs[i] = tanhf(z) * W_a2[h];
  }
  __syncthreads();
  if (t < N_ * K_) {
    float a = b_a2[0];
    for (int h = 0; h < 32; ++h) a += zs[t * 32 + h];
    As[t] = (cnts[t] > 0) ? a : -100000.f;
  }
  __syncthreads();
  if (t < N_) {
    float mx = -3.4e38f;
    for (int k = 0; k < K_; ++k) mx = fmaxf(mx, As[t * K_ + k]);
    float ssum = 0.f;
    float e[K_];
    for (int k = 0; k < K_; ++k) { e[k] = expf(As[t * K_ + k] - mx); ssum += e[k]; }
    for (int k = 0; k < K_; ++k) wa[t * K_ + k] = e[k] / ssum;
  }
  __syncthreads();
  {
    const int n = t >> 6, j = t & 63;
    float s = 0.f;
    for (int k = 0; k < K_; ++k) s += xc[(n * K_ + k) * DH + j] * wa[n * K_ + k];
    pooled[t] = s;
  }
  __syncthreads();
  if (t < N_ * 32) {
    const int n = t >> 5, o = t & 31;
    float s = b_out[o];
    for (int j = 0; j < DH; ++j) s += pooled[n * DH + j] * W_out[j * 32 + o];
    enc_cls[n * 32 + o] = fmaxf(s, 0.f);
  }
}

extern "C" void kernel_launch(void* const* d_in, const int* in_sizes, int n_in,
                              void* d_out, int out_size, void* d_ws, size_t ws_size,
                              hipStream_t stream) {
  const float* x         = (const float*)d_in[0];
  const float* centroids = (const float*)d_in[1];
  const float* W_pre     = (const float*)d_in[2];
  const float* b_pre     = (const float*)d_in[3];
  const float* W_a1      = (const float*)d_in[4];
  const float* b_a1      = (const float*)d_in[5];
  const float* W_a2      = (const float*)d_in[6];
  const float* b_a2      = (const float*)d_in[7];
  const float* W_out     = (const float*)d_in[8];
  const float* b_out     = (const float*)d_in[9];

  float* out     = (float*)d_out;
  float* ws      = (float*)d_ws;
  float* enc_cls = out;
  float* out1    = out + N_ * 32;
  float* out2    = out + N_ * 32 + (size_t)N_ * P_ * DH;

  hipLaunchKernelGGL(k_pre, dim3(81), dim3(512), 0, stream, W_pre, centroids, ws);
  hipLaunchKernelGGL(k_main, dim3((P_ + BP - 1) / BP, N_), dim3(256), 0, stream,
                     x, b_pre, out1, out2, ws);
  hipLaunchKernelGGL(k_final, dim3(1), dim3(256), 0, stream,
                     W_a1, b_a1, W_a2, b_a2, W_out, b_out, ws, enc_cls);
}